// Round 9
// baseline (327.999 us; speedup 1.0000x reference)
//
#include <hip/hip_runtime.h>

// Problem constants
#define B_N    64
#define S_LEN  1024
#define EMB    300
#define EMB_P  304              // padded token stride (halves) -> 608B, 16B-aligned
#define NGRAM  5
#define WPAD   1024
#define MTOT   (B_N * WPAD)     // 65536 rows
#define K1P    1536             // padded K for layer 1 (5*304 = 1520 -> 1536)
#define H0     512
#define H1D    256
#define H2D    128
#define NK1    (K1P / 32)       // 48 B-frag chunks for layer 1
#define NSTEP1 (K1P / 64)       // 24 K-loop steps (BK=64)

#define GATHER_BLOCKS ((MTOT * (EMB_P / 4)) / 256)   // 19456
#define WPREP_THREADS (H0 * K1P + H1D * H0 + H2D * H1D)
#define WPREP_BLOCKS  ((WPREP_THREADS + 255) / 256)

typedef _Float16 half8 __attribute__((ext_vector_type(8)));
typedef float  floatx4 __attribute__((ext_vector_type(4)));

typedef const __attribute__((address_space(1))) void* gptr_t;
typedef __attribute__((address_space(3))) void* sptr_t;

__device__ __forceinline__ void gload16(const void* g, void* s) {
  __builtin_amdgcn_global_load_lds((gptr_t)g, (sptr_t)s, 16, 0, 0);
}

// ---- fused prep: gather table[x]->fp16, zero out, weights -> frag-major
// Frag-major: Bf[((n16*nK + k>>5)*64 + ((k>>3)&3)*16 + (n&15))*8 + (k&7)]
__global__ void prep_kernel(const int* __restrict__ x,
                            const float* __restrict__ table,
                            _Float16* __restrict__ emb,
                            float* __restrict__ out,
                            const float* __restrict__ Ws,
                            const float* __restrict__ W1,
                            const float* __restrict__ W2,
                            _Float16* __restrict__ Bf1,
                            _Float16* __restrict__ Bf2,
                            _Float16* __restrict__ Bf3) {
  const int bid = blockIdx.x;
  if (bid < GATHER_BLOCKS) {
    if (bid < 32) out[bid * 256 + threadIdx.x] = 0.0f;  // zero 8192 outputs
    const int CH = EMB_P / 4;  // 76
    int tid = bid * 256 + threadIdx.x;
    int tok = tid / CH;
    int c   = tid - tok * CH;
    int e   = c << 2;
    _Float16 h0, h1, h2, h3;
    if (e < EMB) {
      float4 v = *(const float4*)(table + (size_t)x[tok] * EMB + e);
      h0 = (_Float16)v.x; h1 = (_Float16)v.y; h2 = (_Float16)v.z; h3 = (_Float16)v.w;
    } else {
      h0 = h1 = h2 = h3 = (_Float16)0.0f;
    }
    union { float2 f2; _Float16 h[4]; } u;
    u.h[0] = h0; u.h[1] = h1; u.h[2] = h2; u.h[3] = h3;
    *(float2*)(emb + (size_t)tok * EMB_P + e) = u.f2;
  } else {
    int tid = (bid - GATHER_BLOCKS) * 256 + threadIdx.x;
    const int NS = H0 * K1P;
    const int N1 = H1D * H0;
    const int N2 = H2D * H1D;
    if (tid < NS) {                       // layer1: coalesced over n
      int n = tid & 511, k = tid >> 9;    // k < 1536
      float v = 0.0f;
      if (k < NGRAM * EMB_P) {
        int tn = k / EMB_P, e = k - tn * EMB_P;
        if (e < EMB) v = Ws[(size_t)(tn * EMB + e) * H0 + n];
      }
      int idx = ((((n >> 4) * NK1 + (k >> 5)) << 6) + (((k >> 3) & 3) << 4) + (n & 15)) * 8 + (k & 7);
      Bf1[idx] = (_Float16)v;
    } else if (tid < NS + N1) {           // layer2: nK=16
      int t = tid - NS;
      int n = t & 255, k = t >> 8;        // k < 512
      float v = W1[(size_t)k * H1D + n];
      int idx = ((((n >> 4) * 16 + (k >> 5)) << 6) + (((k >> 3) & 3) << 4) + (n & 15)) * 8 + (k & 7);
      Bf2[idx] = (_Float16)v;
    } else if (tid < NS + N1 + N2) {      // layer3: nK=8
      int t = tid - (NS + N1);
      int n = t & 127, k = t >> 7;        // k < 256
      float v = W2[(size_t)k * H2D + n];
      int idx = ((((n >> 4) * 8 + (k >> 5)) << 6) + (((k >> 3) & 3) << 4) + (n & 15)) * 8 + (k & 7);
      Bf3[idx] = (_Float16)v;
    }
  }
}

// ------------------------- GEMM1: 128M x 256N tile, BK=64, 4 waves (2x2,
// each 64M x 128N, acc 4x8). A LDS-staged (dbuf, XOR-swizzle, conflict-free),
// B streamed from frag-major global (coalesced 1KB loads). Long MFMA phase
// (64 mfma/wave/step) amortizes the per-step barrier + load latency.
// Epilogue: acc -> LDS -> coalesced dwordx4 frag-major h1f stores (2 passes).
__global__ __launch_bounds__(256, 2)
void gemm1(const _Float16* __restrict__ A, const _Float16* __restrict__ Bf,
           const float* __restrict__ bias, _Float16* __restrict__ Cf) {
  __shared__ _Float16 sA[2][128 * 64];   // 2 x 16 KB

  const int tid  = threadIdx.x;
  const int wave = tid >> 6, lane = tid & 63;
  const int wr   = wave >> 1, wc = wave & 1;
  const int quad = lane >> 4, l16 = lane & 15;

  const int perX = gridDim.x >> 3;                   // 1024 blocks -> 128
  const int L  = (blockIdx.x & 7) * perX + (blockIdx.x >> 3);
  const int mt = L >> 1, nt = L & 1;                 // nTiles = 2
  const long mBase = (long)mt << 7;
  const int  nBase = nt << 8;                        // 256-wide N tile

  // A staging: lane -> (row = srow0 + 32p, slot = lane&7); fetches global
  // chunk c = slot ^ (row&7) (XOR swizzle). LDS dst = uniform + lane*16B.
  const int srow0  = (wave << 3) + (lane >> 3);  // 0..31
  const int schunk = lane & 7;
  const _Float16* aG[4];
  int sOff[4];
#pragma unroll
  for (int p = 0; p < 4; p++) {
    int row = (p << 5) + srow0;
    int c   = schunk ^ (row & 7);
    aG[p]   = A + (mBase + row) * EMB_P + (c << 3);
    sOff[p] = (row << 6) + (schunk << 3);
  }

  // B frag pointers: wave covers cols wc*128 .. wc*128+127 of the 256 tile
  const _Float16* bG[8];
#pragma unroll
  for (int j = 0; j < 8; j++)
    bG[j] = Bf + (((size_t)(((nBase >> 4) + (wc << 3) + j) * NK1)) << 9) + (lane << 3);

  // A-frag LDS offsets: row r, wanted chunk s*4+quad, XOR-unswizzle
  int aOff[2][4];
#pragma unroll
  for (int s = 0; s < 2; s++)
#pragma unroll
    for (int i = 0; i < 4; i++) {
      int r    = (wr << 6) + (i << 4) + l16;
      int slot = ((s << 2) + quad) ^ (l16 & 7);
      aOff[s][i] = (r << 6) + (slot << 3);
    }

  floatx4 acc[4][8] = {};

#pragma unroll
  for (int p = 0; p < 4; p++) gload16(aG[p], &sA[0][sOff[p]]);

#pragma unroll 2
  for (int kk = 0; kk < NSTEP1; kk++) {
    const int cur = kk & 1;
    __syncthreads();
    if (kk + 1 < NSTEP1) {
      const int ko = (kk + 1) << 6;
#pragma unroll
      for (int p = 0; p < 4; p++) gload16(aG[p] + ko, &sA[cur ^ 1][sOff[p]]);
    }
#pragma unroll
    for (int s = 0; s < 2; s++) {
      half8 bFr[8];
#pragma unroll
      for (int j = 0; j < 8; j++)
        bFr[j] = *(const half8*)(bG[j] + (size_t)(((kk << 1) + s) << 9));
      half8 aFr[4];
#pragma unroll
      for (int i = 0; i < 4; i++)
        aFr[i] = *(const half8*)(&sA[cur][aOff[s][i]]);
#pragma unroll
      for (int i = 0; i < 4; i++)
#pragma unroll
        for (int j = 0; j < 8; j++)
          acc[i][j] = __builtin_amdgcn_mfma_f32_16x16x32_f16(aFr[i], bFr[j], acc[i][j], 0, 0, 0);
    }
  }

  // ---- epilogue: 2 passes (cols h*128..h*128+127), acc -> LDS -> dwordx4
  _Float16* cs = &sA[0][0];  // 16384 halves = 32 KB = one 128x128 fp16 tile
#pragma unroll
  for (int h = 0; h < 2; h++) {
    __syncthreads();
    if (wc == h) {
#pragma unroll
      for (int j = 0; j < 8; j++) {
        int cl2 = (j << 4) + l16;            // 0..127 within pass
        float bv = bias[nBase + (h << 7) + cl2];
        int ksl = cl2 >> 5;
        int sub_hi = ((cl2 >> 3) & 3) << 4;
        int c7 = cl2 & 7;
#pragma unroll
        for (int i = 0; i < 4; i++) {
          int m16l = (wr << 2) + i;
#pragma unroll
          for (int r = 0; r < 4; r++) {
            int ml = (quad << 2) + r;
            cs[(((m16l << 2) + ksl) << 9) + ((sub_hi + ml) << 3) + c7] =
                (_Float16)(acc[i][j][r] + bv);
          }
        }
      }
    }
    __syncthreads();
#pragma unroll
    for (int it = 0; it < 8; it++) {
      int cid = (it << 2) + wave;            // 0..31: (m16l, ksl)
      int m16l = cid >> 2, ksl = cid & 3;
      int kch = (nt << 3) + (h << 2) + ksl;  // global k-chunk of 16
      size_t g = ((size_t)(((mt << 3) + m16l) * 16 + kch) << 9) + (lane << 3);
      *(half8*)(Cf + g) = *(const half8*)(cs + (cid << 9) + (lane << 3));
    }
  }
}

// ------------------- fused GEMM2+GEMM3: h2 never leaves the CU.
__global__ __launch_bounds__(256, 2)
void gemm23(const _Float16* __restrict__ Af, const _Float16* __restrict__ B2,
            const _Float16* __restrict__ B3, const float* __restrict__ bias1,
            const float* __restrict__ bias2, float* __restrict__ out,
            const int* __restrict__ lengths) {
  __shared__ _Float16 sH[32768];   // 64 KB: [m16l(8)][ks(8)][sub(64)][8]
  __shared__ float red[2][128];

  const int tid  = threadIdx.x;
  const int wave = tid >> 6, lane = tid & 63;
  const int wr   = wave >> 1, wc = wave & 1;
  const int quad = lane >> 4, l16 = lane & 15;
  const int mt = blockIdx.x;

  const _Float16* aR[4];
#pragma unroll
  for (int i = 0; i < 4; i++)
    aR[i] = Af + (((size_t)((mt << 3) + (wr << 2) + i) * 16) << 9) + (lane << 3);
  const _Float16* bR[8];
#pragma unroll
  for (int j = 0; j < 8; j++)
    bR[j] = B2 + (((size_t)((wc << 3) + j) * 16) << 9) + (lane << 3);

  floatx4 acc2[4][8] = {};
#pragma unroll 2
  for (int kk = 0; kk < 16; kk++) {
    const size_t ko = (size_t)kk << 9;
    half8 aF[4], bF[8];
#pragma unroll
    for (int i = 0; i < 4; i++) aF[i] = *(const half8*)(aR[i] + ko);
#pragma unroll
    for (int j = 0; j < 8; j++) bF[j] = *(const half8*)(bR[j] + ko);
#pragma unroll
    for (int i = 0; i < 4; i++)
#pragma unroll
      for (int j = 0; j < 8; j++)
        acc2[i][j] = __builtin_amdgcn_mfma_f32_16x16x32_f16(aF[i], bF[j], acc2[i][j], 0, 0, 0);
  }

  // h2 tile -> LDS frag-major, +bias1, relu
#pragma unroll
  for (int j = 0; j < 8; j++) {
    int n = (wc << 7) + (j << 4) + l16;    // h2 col 0..255
    float bv = bias1[n];
    int ks = n >> 5;
    int sub_hi = ((n >> 3) & 3) << 4;
    int c7 = n & 7;
#pragma unroll
    for (int i = 0; i < 4; i++) {
      int m16l = (wr << 2) + i;
#pragma unroll
      for (int r = 0; r < 4; r++) {
        int ml = (quad << 2) + r;
        sH[(((m16l << 3) + ks) << 9) + ((sub_hi + ml) << 3) + c7] =
            (_Float16)fmaxf(acc2[i][j][r] + bv, 0.0f);
      }
    }
  }
  __syncthreads();

  // Phase B: G3 (K=256 from LDS)
  const _Float16* b3R[4];
#pragma unroll
  for (int j = 0; j < 4; j++)
    b3R[j] = B3 + (((size_t)((wc << 2) + j) * 8) << 9) + (lane << 3);

  floatx4 acc3[4][4] = {};
#pragma unroll
  for (int ks = 0; ks < 8; ks++) {
    half8 aF[4], bF[4];
#pragma unroll
    for (int i = 0; i < 4; i++)
      aF[i] = *(const half8*)(sH + (((((wr << 2) + i) << 3) + ks) << 9) + (lane << 3));
#pragma unroll
    for (int j = 0; j < 4; j++) bF[j] = *(const half8*)(b3R[j] + ((size_t)ks << 9));
#pragma unroll
    for (int i = 0; i < 4; i++)
#pragma unroll
      for (int j = 0; j < 4; j++)
        acc3[i][j] = __builtin_amdgcn_mfma_f32_16x16x32_f16(aF[i], bF[j], acc3[i][j], 0, 0, 0);
  }

  // fused relu + ragged-mean pooling (C/D: col=lane&15, row=quad*4+r)
  int b = mt >> 3;
  int validw = lengths[b] - (NGRAM - 1);
  float inv = 1.0f / (float)validw;
  int wBase = ((mt & 7) << 7) + (wr << 6);
#pragma unroll
  for (int j = 0; j < 4; j++) {
    int col = (wc << 6) + (j << 4) + l16;
    float bv = bias2[col];
    float p = 0.0f;
#pragma unroll
    for (int i = 0; i < 4; i++) {
#pragma unroll
      for (int r = 0; r < 4; r++) {
        int w = wBase + (i << 4) + (quad << 2) + r;
        float v = fmaxf(acc3[i][j][r] + bv, 0.0f);
        p += (w < validw) ? v : 0.0f;
      }
    }
    p *= inv;
    p += __shfl_xor(p, 16, 64);
    p += __shfl_xor(p, 32, 64);
    if (quad == 0) red[wr][col] = p;
  }
  __syncthreads();
  if (tid < 128) atomicAdd(out + b * H2D + tid, red[0][tid] + red[1][tid]);
}

// ---------------------------------------------------------------- launcher
extern "C" void kernel_launch(void* const* d_in, const int* in_sizes, int n_in,
                              void* d_out, int out_size, void* d_ws, size_t ws_size,
                              hipStream_t stream) {
  const int*   x       = (const int*)d_in[0];
  const int*   lengths = (const int*)d_in[1];
  const float* table   = (const float*)d_in[2];
  const float* W_slide = (const float*)d_in[3];
  const float* b_slide = (const float*)d_in[4];
  const float* W1      = (const float*)d_in[5];
  const float* b1      = (const float*)d_in[6];
  const float* W2      = (const float*)d_in[7];
  const float* b2      = (const float*)d_in[8];
  float* out = (float*)d_out;

  // workspace (halves). emb +4096 pad: tail windows read past logical end
  // (finite poison * masked rows, see pooling mask).
  _Float16* ws  = (_Float16*)d_ws;
  _Float16* emb = ws;                                   // 64*1024*304
  _Float16* Bf1 = emb + (size_t)MTOT * EMB_P + 4096;    // 512*1536 frag-major
  _Float16* Bf2 = Bf1 + (size_t)H0 * K1P;               // 256*512  frag-major
  _Float16* Bf3 = Bf2 + (size_t)H1D * H0;               // 128*256  frag-major
  _Float16* h1f = Bf3 + (size_t)H2D * H1D;              // 65536*512 frag-major

  prep_kernel<<<GATHER_BLOCKS + WPREP_BLOCKS, 256, 0, stream>>>(
      x, table, emb, out, W_slide, W1, W2, Bf1, Bf2, Bf3);
  // L1: win @ W_slide + b_slide -> h1f (frag-major), 128x256 tiles
  gemm1<<<(MTOT / 128) * (H0 / 256), 256, 0, stream>>>(emb, Bf1, b_slide, h1f);
  // L2+L3 fused: relu(h1@W1+b1) -> LDS -> relu(.@W2+b2) -> masked-mean pool
  gemm23<<<MTOT / 128, 256, 0, stream>>>(h1f, Bf2, Bf3, b1, b2, out, lengths);
}